// Round 14
// baseline (147.692 us; speedup 1.0000x reference)
//
#include <hip/hip_runtime.h>

// Fused attention block for MI355X (gfx950).
// Pipeline: k_prep(conv x,W) -> GEMM1(qkv, BK=64 2-blk/CU dbuf) -> k_post(RMS/RoPE/
//           shift/gates/vT) -> LDS-staged windowed flash attention (K/Q/V staged,
//           split vmcnt) -> GEMM2 -> d_out

#define TSEQ 8192
#define DIMM 1024
#define NHEAD 8
#define HD 128
#define ATTN_SCALE 0.1f
#define RMS_EPS 1.1920929e-07f

typedef __bf16 bfx2 __attribute__((ext_vector_type(2)));
typedef __bf16 bfx4 __attribute__((ext_vector_type(4)));
typedef __bf16 bfx8 __attribute__((ext_vector_type(8)));
typedef float f32x4 __attribute__((ext_vector_type(4)));
typedef short s16x4 __attribute__((ext_vector_type(4)));

#define GLDS16(g, l)                                                         \
  __builtin_amdgcn_global_load_lds(                                          \
      (const __attribute__((address_space(1))) void*)(g),                    \
      (__attribute__((address_space(3))) void*)(l), 16, 0, 0)

__device__ __forceinline__ float sig_(float z) { return 1.0f / (1.0f + __expf(-z)); }

// ---------------- fused f32 -> bf16 conversions (x and weights) ----------------
__global__ void k_prep(const float4* __restrict__ x, const float4* __restrict__ w,
                       const float* __restrict__ lam, bfx4* __restrict__ xb,
                       bfx4* __restrict__ w1b, bfx4* __restrict__ w2b) {
  const int nx = TSEQ * DIMM / 4;
  const int nw = 4096 * 1024 / 4;
  const float l0 = lam[0], l1 = lam[1];
  int i = blockIdx.x * blockDim.x + threadIdx.x;
  int stride = gridDim.x * blockDim.x;
  for (; i < nx + nw; i += stride) {
    if (i < nx) {
      float4 v = x[i];
      bfx4 o;
      o[0] = (__bf16)v.x; o[1] = (__bf16)v.y; o[2] = (__bf16)v.z; o[3] = (__bf16)v.w;
      xb[i] = o;
    } else {
      int j = i - nx;
      int row = (j * 4) >> 10;
      float s = (row < 3 * DIMM) ? l0 : l1;
      float4 v = w[j];
      bfx4 o;
      o[0] = (__bf16)(s * v.x); o[1] = (__bf16)(s * v.y);
      o[2] = (__bf16)(s * v.z); o[3] = (__bf16)(s * v.w);
      if (row < 3 * DIMM) w1b[j] = o;
      else                w2b[j - 3 * DIMM * DIMM / 4] = o;
    }
  }
}

// ---------------- 2-blocks/CU GEMM: C[M,N] = A[M,K] * B[N,K]^T ----------------
// 128x128 tile, BK=64, 4 waves (2x2, wave tile 64x64), double-buffered 64KB LDS
// -> 2 blocks/CU co-resident (inter-block overlap, m114 mechanism).
template <typename CT>
__global__ __launch_bounds__(256, 2) void k_gemm2b(const __bf16* __restrict__ A,
                                                   const __bf16* __restrict__ B,
                                                   CT* __restrict__ C,
                                                   int M, int N, int K) {
  __shared__ __align__(16) __bf16 ldsb[2][256 * 64];
  const int tid = threadIdx.x;
  const int wave = tid >> 6, lane = tid & 63;
  const int wm = wave >> 1, wn = wave & 1;
  const int lr = lane & 15, lg = lane >> 4;
  const int bm = blockIdx.x, bn = blockIdx.y;

  const int srow = tid >> 3;
  const int scol = ((tid & 7) ^ (srow & 7)) * 8;
  const __bf16* Ag = A + (size_t)(bm * 128 + srow) * K + scol;
  const __bf16* Bg = B + (size_t)(bn * 128 + srow) * K + scol;

  char* buf0 = (char*)&ldsb[0][0];
  char* buf1 = (char*)&ldsb[1][0];

  auto stage = [&](int kt, char* buf) {
#pragma unroll
    for (int L = 0; L < 4; L++)
      GLDS16(Ag + (size_t)(L * 32) * K + kt * 64, buf + L * 4096 + wave * 1024);
#pragma unroll
    for (int L = 0; L < 4; L++)
      GLDS16(Bg + (size_t)(L * 32) * K + kt * 64, buf + 16384 + L * 4096 + wave * 1024);
  };

  const int aoffs = (wm * 64 + lr) * 128;
  const int boffs = 16384 + (wn * 64 + lr) * 128;
  const int s0 = (lg ^ (lr & 7)) * 16;
  const int s1 = ((4 + lg) ^ (lr & 7)) * 16;

  f32x4 acc[4][4] = {};

#define VMC0() asm volatile("s_waitcnt vmcnt(0)" ::: "memory")
#define BAR() __builtin_amdgcn_s_barrier()

  stage(0, buf0);
  VMC0(); BAR();

  const int NT = K / 64;
  for (int t = 0; t < NT; t++) {
    char* cur = (t & 1) ? buf1 : buf0;
    char* nxt = (t & 1) ? buf0 : buf1;
    if (t + 1 < NT) stage(t + 1, nxt);
    bfx8 af[4][2], bfr[4][2];
#pragma unroll
    for (int f = 0; f < 4; f++) {
      const char* p = cur + aoffs + f * 2048;
      af[f][0] = *(const bfx8*)(p + s0);
      af[f][1] = *(const bfx8*)(p + s1);
    }
#pragma unroll
    for (int f = 0; f < 4; f++) {
      const char* p = cur + boffs + f * 2048;
      bfr[f][0] = *(const bfx8*)(p + s0);
      bfr[f][1] = *(const bfx8*)(p + s1);
    }
    __builtin_amdgcn_s_setprio(1);
#pragma unroll
    for (int i = 0; i < 4; i++)
#pragma unroll
      for (int j = 0; j < 4; j++) {
        acc[i][j] = __builtin_amdgcn_mfma_f32_16x16x32_bf16(af[i][0], bfr[j][0], acc[i][j], 0, 0, 0);
        acc[i][j] = __builtin_amdgcn_mfma_f32_16x16x32_bf16(af[i][1], bfr[j][1], acc[i][j], 0, 0, 0);
      }
    __builtin_amdgcn_s_setprio(0);
    VMC0(); BAR();
  }

  const int rbase = bm * 128 + wm * 64 + lg * 4;
  const int cbase = bn * 128 + wn * 64 + lr;
#pragma unroll
  for (int f = 0; f < 4; f++)
#pragma unroll
    for (int rr = 0; rr < 4; rr++) {
      size_t rowoff = (size_t)(rbase + f * 16 + rr) * N + cbase;
#pragma unroll
      for (int nf = 0; nf < 4; nf++) C[rowoff + nf * 16] = (CT)acc[f][nf][rr];
    }
#undef VMC0
#undef BAR
}

// ---------------- merged postprocess: gates + q/k RMS/RoPE/shift + v-gate/vT ----------------
__global__ __launch_bounds__(512) void k_post(
    const __bf16* __restrict__ qkv, const float* __restrict__ x,
    const float* __restrict__ ve, const float* __restrict__ f1,
    const float* __restrict__ f2, const float* __restrict__ agw,
    const float* __restrict__ vgw, const int* __restrict__ koff_p,
    __bf16* __restrict__ qb, __bf16* __restrict__ kb,
    __bf16* __restrict__ vT, float* __restrict__ ag) {
  __shared__ float vg_lds[32][8];
  __shared__ __bf16 vtile[HD][36];
  const int t0 = blockIdx.x * 32;
  const int tid = threadIdx.x;
  const int h = tid >> 6, l = tid & 63;
  const int d0 = 2 * l;
  const int koff = *koff_p;

  if (tid < 256) {
    const int tl = tid >> 3, hh = tid & 7;
    const int t = t0 + tl;
    float za = 0.0f, zg = 0.0f;
#pragma unroll
    for (int j = 0; j < 12; j++) {
      float xv = x[(size_t)t * DIMM + j];
      za += xv * agw[hh * 12 + j];
      zg += xv * vgw[hh * 12 + j];
    }
    ag[(size_t)t * NHEAD + hh] = sig_(za);
    vg_lds[tl][hh] = 2.0f * sig_(zg);
  }

#pragma unroll 2
  for (int tl = 0; tl < 32; tl++) {
    const int t = t0 + tl;
    const size_t qoff = (size_t)t * (3 * DIMM) + h * HD;

    bfx2 qv = *(const bfx2*)&qkv[qoff + d0];
    bfx2 kv = *(const bfx2*)&qkv[qoff + DIMM + d0];
    float q0 = (float)qv[0], q1 = (float)qv[1];
    float k0 = (float)kv[0], k1 = (float)kv[1];

    float sq = q0 * q0 + q1 * q1;
    float sk = k0 * k0 + k1 * k1;
#pragma unroll
    for (int off = 32; off; off >>= 1) {
      sq += __shfl_xor(sq, off);
      sk += __shfl_xor(sk, off);
    }
    float rq = rsqrtf(sq * (1.0f / 128.0f) + RMS_EPS);
    float rk = rsqrtf(sk * (1.0f / 128.0f) + RMS_EPS);
    q0 *= rq; q1 *= rq; k0 *= rk; k1 *= rk;

    float2 cc = *(const float2*)&f1[(size_t)t * HD + d0];
    float2 ss = *(const float2*)&f2[(size_t)t * HD + d0];
    float rq0 = cc.x * q0 + ss.x * q1, rq1 = cc.y * q1 + ss.y * q0;
    float rk0 = cc.x * k0 + ss.x * k1, rk1 = cc.y * k1 + ss.y * k0;

    bfx2 qo; qo[0] = (__bf16)rq0; qo[1] = (__bf16)rq1;
    *(bfx2*)&qb[(size_t)t * DIMM + h * HD + d0] = qo;

    bfx2 ko2; ko2[0] = (__bf16)rk0; ko2[1] = (__bf16)rk1;
    const size_t kcol = (size_t)h * HD + d0;
    if (!koff || l < 32) {
      *(bfx2*)&kb[(size_t)t * DIMM + kcol] = ko2;
    } else {
      if (t + 1 < TSEQ) *(bfx2*)&kb[(size_t)(t + 1) * DIMM + kcol] = ko2;
      if (t == 0)       *(bfx2*)&kb[kcol] = ko2;
    }
  }
  __syncthreads();

  const int w = tid >> 6;
  const int dout = tid >> 2, tof = (tid & 3) * 8;
  for (int hh = 0; hh < 8; hh++) {
#pragma unroll
    for (int it = 0; it < 4; it++) {
      const int tl = w * 4 + it;
      const int t = t0 + tl;
      const size_t voff = (size_t)t * (3 * DIMM) + 2 * DIMM + hh * HD;
      float va = (float)qkv[voff + l];
      float vb = (float)qkv[voff + l + 64];
      float vea = ve[(size_t)t * DIMM + hh * HD + l];
      float veb = ve[(size_t)t * DIMM + hh * HD + l + 64];
      float gv = vg_lds[tl][hh];
      vtile[l][tl]      = (__bf16)(va + gv * vea);
      vtile[l + 64][tl] = (__bf16)(vb + gv * veb);
    }
    __syncthreads();
    {
      bfx4 a0 = *(const bfx4*)&vtile[dout][tof];
      bfx4 a1 = *(const bfx4*)&vtile[dout][tof + 4];
      bfx8 p0;
      p0[0] = a0[0]; p0[1] = a0[1]; p0[2] = a0[2]; p0[3] = a0[3];
      p0[4] = a1[0]; p0[5] = a1[1]; p0[6] = a1[2]; p0[7] = a1[3];
      *(bfx8*)&vT[(size_t)(hh * HD + dout) * TSEQ + t0 + tof] = p0;
    }
    __syncthreads();
  }
}

// ---------------- LDS-staged windowed varlen flash attention (K/Q/V staged) ----------------
// grid (TSEQ/128, NHEAD), 512 threads; 160KB LDS (K 64K + V 64K + Q 32K).
// Issue: seg-loads, K(8), Q(4), V(8) glds -> vmcnt(8) [K+Q landed, V in flight]
// -> barrier -> QK^T+softmax (hides V) -> vmcnt(0) -> barrier -> PV.
__global__ __launch_bounds__(512, 1) void k_attn3(
    const __bf16* __restrict__ qb, const __bf16* __restrict__ kb,
    const __bf16* __restrict__ vT, const float* __restrict__ ag,
    const int* __restrict__ sl, int ns, __bf16* __restrict__ yb) {
  __shared__ __align__(16) char kls[65536];  // K: 256 rows x 256B (swizzled slots)
  __shared__ __align__(16) char vls[65536];  // V: 128 d-rows x 512B (swizzled slots)
  __shared__ __align__(16) char qls[32768];  // Q: 128 rows x 256B (swizzled slots)
  const int n = blockIdx.x, h = blockIdx.y;
  const int tid = threadIdx.x;
  const int w = tid >> 6, l = tid & 63;
  const int lr = l & 15, lg = l >> 4;
  const int q0r = n * 128 + w * 16;
  const int kbase = q0r - 128;
  const int kbb = n * 128 - 128;
  const int q = q0r + lr;
  const int kfs = (q0r < 128) ? ((128 - q0r) >> 4) : 0;

  // segment lower bound per q-row (scalar-ish loads; consumed before glds issue)
  int segs = 0;
  for (int i = 0; i < ns; i++) {
    int v = sl[i];
    segs = (v <= q) ? ((v > segs) ? v : segs) : segs;
  }
  int klo = q - 128;
  if (segs > klo) klo = segs;
  if (klo < 0) klo = 0;
  __builtin_amdgcn_sched_barrier(0);

  // ---- stage K: 8 rounds x 8KB ----
  {
    const int rr_ = tid >> 4;
    const int slot = tid & 15;
#pragma unroll
    for (int r = 0; r < 8; r++) {
      const int rel = r * 32 + rr_;
      int grow = kbb + rel;
      grow = grow < 0 ? 0 : grow;
      const int slotp = slot ^ (rel & 15);
      GLDS16(kb + (size_t)grow * DIMM + h * HD + slotp * 8,
             kls + r * 8192 + w * 1024);
    }
  }
  // ---- stage Q: 4 rounds x 8KB ----
  {
    const int rr_ = tid >> 4;
    const int slot = tid & 15;
#pragma unroll
    for (int r = 0; r < 4; r++) {
      const int rel = r * 32 + rr_;                  // 0..127 block-relative q row
      const int slotp = slot ^ (rel & 15);
      GLDS16(qb + (size_t)(n * 128 + rel) * DIMM + h * HD + slotp * 8,
             qls + r * 8192 + w * 1024);
    }
  }
  // ---- stage V: 8 rounds x 8KB ----
  {
    const int slot = l & 31;
#pragma unroll
    for (int r = 0; r < 8; r++) {
      const int d = r * 16 + w * 2 + (l >> 5);
      const int slotp = slot ^ (d & 15);
      int tsrc = kbb + slotp * 8;
      tsrc = tsrc < 0 ? 0 : tsrc;
      GLDS16(vT + (size_t)(h * HD + d) * TSEQ + tsrc,
             vls + r * 8192 + w * 1024);
    }
  }

  __builtin_amdgcn_sched_barrier(0);
  asm volatile("s_waitcnt vmcnt(8)" ::: "memory");  // K+Q landed; V in flight
  __builtin_amdgcn_sched_barrier(0);
  __builtin_amdgcn_s_barrier();

  // Q fragments from LDS
  const int qrow = w * 16 + lr;
  const char* qp = qls + qrow * 256;
  bfx8 qf[4];
#pragma unroll
  for (int ds = 0; ds < 4; ds++)
    qf[ds] = *(const bfx8*)(qp + (((ds * 4 + lg) ^ lr) * 16));

  // ---- S^T = K Q^T over the 144-key window (K frags from LDS) ----
  const int kswz = lr << 4;
  f32x4 sf[9] = {};
#pragma unroll
  for (int kf = 0; kf < 9; kf++) {
    if (kf >= kfs) {
      const int relrow = w * 16 + kf * 16 + lr;
      const char* kp = kls + relrow * 256;
      bfx8 k0 = *(const bfx8*)(kp + ((lg * 16) ^ kswz));
      bfx8 k1 = *(const bfx8*)(kp + ((64 + lg * 16) ^ kswz));
      bfx8 k2 = *(const bfx8*)(kp + ((128 + lg * 16) ^ kswz));
      bfx8 k3 = *(const bfx8*)(kp + ((192 + lg * 16) ^ kswz));
      sf[kf] = __builtin_amdgcn_mfma_f32_16x16x32_bf16(k0, qf[0], sf[kf], 0, 0, 0);
      sf[kf] = __builtin_amdgcn_mfma_f32_16x16x32_bf16(k1, qf[1], sf[kf], 0, 0, 0);
      sf[kf] = __builtin_amdgcn_mfma_f32_16x16x32_bf16(k2, qf[2], sf[kf], 0, 0, 0);
      sf[kf] = __builtin_amdgcn_mfma_f32_16x16x32_bf16(k3, qf[3], sf[kf], 0, 0, 0);
    }
  }

  // mask + scale
#pragma unroll
  for (int kf = 0; kf < 9; kf++)
#pragma unroll
    for (int rr = 0; rr < 4; rr++) {
      int k = kbase + kf * 16 + lg * 4 + rr;
      bool valid = (k >= klo) && (k <= q);
      sf[kf][rr] = valid ? sf[kf][rr] * ATTN_SCALE : -1e30f;
    }

  float mx = -1e30f;
#pragma unroll
  for (int kf = 0; kf < 9; kf++)
#pragma unroll
    for (int rr = 0; rr < 4; rr++) mx = fmaxf(mx, sf[kf][rr]);
  mx = fmaxf(mx, __shfl_xor(mx, 16));
  mx = fmaxf(mx, __shfl_xor(mx, 32));

  float lsum = 0.0f;
#pragma unroll
  for (int kf = 0; kf < 9; kf++)
#pragma unroll
    for (int rr = 0; rr < 4; rr++) {
      float p = __expf(sf[kf][rr] - mx);
      sf[kf][rr] = p;
      lsum += p;
    }
  lsum += __shfl_xor(lsum, 16);
  lsum += __shfl_xor(lsum, 32);

  __builtin_amdgcn_sched_barrier(0);
  asm volatile("s_waitcnt vmcnt(0)" ::: "memory");  // V landed
  __builtin_amdgcn_sched_barrier(0);
  __builtin_amdgcn_s_barrier();

  // ---- O^T = V^T P^T via 16x16x16 MFMAs (V frags from LDS) ----
  f32x4 o[8] = {};
#pragma unroll
  for (int kf = 0; kf < 9; kf++) {
    if (kf >= kfs) {
      bfx4 pc;
      pc[0] = (__bf16)sf[kf][0]; pc[1] = (__bf16)sf[kf][1];
      pc[2] = (__bf16)sf[kf][2]; pc[3] = (__bf16)sf[kf][3];
      s16x4 pb = *(s16x4*)&pc;
      const int tof = (w * 32 + kf * 32 + lg * 8) ^ kswz;
#pragma unroll
      for (int nf = 0; nf < 8; nf++) {
        s16x4 vf = *(const s16x4*)(vls + (nf * 16 + lr) * 512 + tof);
        o[nf] = __builtin_amdgcn_mfma_f32_16x16x16bf16_1k(vf, pb, o[nf], 0, 0, 0);
      }
    }
  }

  const float sc = ag[(size_t)q * NHEAD + h] / lsum;
#pragma unroll
  for (int nf = 0; nf < 8; nf++) {
    bfx4 st;
#pragma unroll
    for (int rr = 0; rr < 4; rr++) st[rr] = (__bf16)(o[nf][rr] * sc);
    *(bfx4*)&yb[(size_t)q * DIMM + h * HD + nf * 16 + lg * 4] = st;
  }
}

// ---------------- launch ----------------
extern "C" void kernel_launch(void* const* d_in, const int* in_sizes, int n_in,
                              void* d_out, int out_size, void* d_ws, size_t ws_size,
                              hipStream_t stream) {
  const float* x   = (const float*)d_in[0];
  const float* qw  = (const float*)d_in[1];
  const float* ve  = (const float*)d_in[2];
  const float* lam = (const float*)d_in[3];
  const float* f1  = (const float*)d_in[4];
  const float* f2  = (const float*)d_in[5];
  const float* agw = (const float*)d_in[6];
  const float* vgw = (const float*)d_in[7];
  const int*   sl  = (const int*)d_in[8];
  const int    ns  = in_sizes[8];
  const int*   koff = (const int*)d_in[10];
  float* out = (float*)d_out;
  char* ws = (char*)d_ws;

  const size_t MB = 1024 * 1024;
  if (ws_size < 105 * MB) return;
  __bf16* xb   = (__bf16*)(ws);
  __bf16* w1b  = (__bf16*)(ws + 16 * MB);
  __bf16* w2b  = (__bf16*)(ws + 22 * MB);
  __bf16* qkvb = (__bf16*)(ws + 24 * MB);
  __bf16* qbuf = (__bf16*)(ws + 72 * MB);
  __bf16* kbuf = (__bf16*)(ws + 88 * MB);
  float*  ag   = (float*)(ws + 104 * MB);
  __bf16* vT   = xb;    // xb dead after GEMM1
  __bf16* ybuf = qkvb;  // qkvb dead after k_post

  k_prep<<<3072, 256, 0, stream>>>((const float4*)x, (const float4*)qw, lam,
                                   (bfx4*)xb, (bfx4*)w1b, (bfx4*)w2b);
  k_gemm2b<__bf16><<<dim3(TSEQ / 128, 3 * DIMM / 128), 256, 0, stream>>>(
      xb, w1b, qkvb, TSEQ, 3 * DIMM, DIMM);
  k_post<<<TSEQ / 32, 512, 0, stream>>>(qkvb, x, ve, f1, f2, agw, vgw, koff,
                                        qbuf, kbuf, vT, ag);
  k_attn3<<<dim3(TSEQ / 128, NHEAD), 512, 0, stream>>>(qbuf, kbuf, vT, ag, sl, ns, ybuf);
  k_gemm2b<float><<<dim3(TSEQ / 128, DIMM / 128), 256, 0, stream>>>(
      ybuf, w2b, out, TSEQ, DIMM, DIMM);
}

// Round 15
// 140.947 us; speedup vs baseline: 1.0479x; 1.0479x over previous
//
#include <hip/hip_runtime.h>

// Fused attention block for MI355X (gfx950).
// Pipeline: k_prep(conv x,W) -> GEMM1(qkv, BK=64 2-blk/CU dbuf) -> k_post(RMS/RoPE/
//           shift/gates/vT) -> LDS-staged windowed flash attention (K/V time-shared
//           64KB LDS, 2 blocks/CU) -> GEMM2 -> d_out

#define TSEQ 8192
#define DIMM 1024
#define NHEAD 8
#define HD 128
#define ATTN_SCALE 0.1f
#define RMS_EPS 1.1920929e-07f

typedef __bf16 bfx2 __attribute__((ext_vector_type(2)));
typedef __bf16 bfx4 __attribute__((ext_vector_type(4)));
typedef __bf16 bfx8 __attribute__((ext_vector_type(8)));
typedef float f32x4 __attribute__((ext_vector_type(4)));
typedef short s16x4 __attribute__((ext_vector_type(4)));

#define GLDS16(g, l)                                                         \
  __builtin_amdgcn_global_load_lds(                                          \
      (const __attribute__((address_space(1))) void*)(g),                    \
      (__attribute__((address_space(3))) void*)(l), 16, 0, 0)

__device__ __forceinline__ float sig_(float z) { return 1.0f / (1.0f + __expf(-z)); }

// ---------------- fused f32 -> bf16 conversions (x and weights) ----------------
__global__ void k_prep(const float4* __restrict__ x, const float4* __restrict__ w,
                       const float* __restrict__ lam, bfx4* __restrict__ xb,
                       bfx4* __restrict__ w1b, bfx4* __restrict__ w2b) {
  const int nx = TSEQ * DIMM / 4;
  const int nw = 4096 * 1024 / 4;
  const float l0 = lam[0], l1 = lam[1];
  int i = blockIdx.x * blockDim.x + threadIdx.x;
  int stride = gridDim.x * blockDim.x;
  for (; i < nx + nw; i += stride) {
    if (i < nx) {
      float4 v = x[i];
      bfx4 o;
      o[0] = (__bf16)v.x; o[1] = (__bf16)v.y; o[2] = (__bf16)v.z; o[3] = (__bf16)v.w;
      xb[i] = o;
    } else {
      int j = i - nx;
      int row = (j * 4) >> 10;
      float s = (row < 3 * DIMM) ? l0 : l1;
      float4 v = w[j];
      bfx4 o;
      o[0] = (__bf16)(s * v.x); o[1] = (__bf16)(s * v.y);
      o[2] = (__bf16)(s * v.z); o[3] = (__bf16)(s * v.w);
      if (row < 3 * DIMM) w1b[j] = o;
      else                w2b[j - 3 * DIMM * DIMM / 4] = o;
    }
  }
}

// ---------------- 2-blocks/CU GEMM: C[M,N] = A[M,K] * B[N,K]^T ----------------
// 128x128 tile, BK=64, 4 waves (2x2, wave tile 64x64), double-buffered 64KB LDS
// -> 2 blocks/CU co-resident (inter-block overlap, m114 mechanism).
template <typename CT>
__global__ __launch_bounds__(256, 2) void k_gemm2b(const __bf16* __restrict__ A,
                                                   const __bf16* __restrict__ B,
                                                   CT* __restrict__ C,
                                                   int M, int N, int K) {
  __shared__ __align__(16) __bf16 ldsb[2][256 * 64];
  const int tid = threadIdx.x;
  const int wave = tid >> 6, lane = tid & 63;
  const int wm = wave >> 1, wn = wave & 1;
  const int lr = lane & 15, lg = lane >> 4;
  const int bm = blockIdx.x, bn = blockIdx.y;

  const int srow = tid >> 3;
  const int scol = ((tid & 7) ^ (srow & 7)) * 8;
  const __bf16* Ag = A + (size_t)(bm * 128 + srow) * K + scol;
  const __bf16* Bg = B + (size_t)(bn * 128 + srow) * K + scol;

  char* buf0 = (char*)&ldsb[0][0];
  char* buf1 = (char*)&ldsb[1][0];

  auto stage = [&](int kt, char* buf) {
#pragma unroll
    for (int L = 0; L < 4; L++)
      GLDS16(Ag + (size_t)(L * 32) * K + kt * 64, buf + L * 4096 + wave * 1024);
#pragma unroll
    for (int L = 0; L < 4; L++)
      GLDS16(Bg + (size_t)(L * 32) * K + kt * 64, buf + 16384 + L * 4096 + wave * 1024);
  };

  const int aoffs = (wm * 64 + lr) * 128;
  const int boffs = 16384 + (wn * 64 + lr) * 128;
  const int s0 = (lg ^ (lr & 7)) * 16;
  const int s1 = ((4 + lg) ^ (lr & 7)) * 16;

  f32x4 acc[4][4] = {};

#define VMC0() asm volatile("s_waitcnt vmcnt(0)" ::: "memory")
#define BAR() __builtin_amdgcn_s_barrier()

  stage(0, buf0);
  VMC0(); BAR();

  const int NT = K / 64;
  for (int t = 0; t < NT; t++) {
    char* cur = (t & 1) ? buf1 : buf0;
    char* nxt = (t & 1) ? buf0 : buf1;
    if (t + 1 < NT) stage(t + 1, nxt);
    bfx8 af[4][2], bfr[4][2];
#pragma unroll
    for (int f = 0; f < 4; f++) {
      const char* p = cur + aoffs + f * 2048;
      af[f][0] = *(const bfx8*)(p + s0);
      af[f][1] = *(const bfx8*)(p + s1);
    }
#pragma unroll
    for (int f = 0; f < 4; f++) {
      const char* p = cur + boffs + f * 2048;
      bfr[f][0] = *(const bfx8*)(p + s0);
      bfr[f][1] = *(const bfx8*)(p + s1);
    }
    __builtin_amdgcn_s_setprio(1);
#pragma unroll
    for (int i = 0; i < 4; i++)
#pragma unroll
      for (int j = 0; j < 4; j++) {
        acc[i][j] = __builtin_amdgcn_mfma_f32_16x16x32_bf16(af[i][0], bfr[j][0], acc[i][j], 0, 0, 0);
        acc[i][j] = __builtin_amdgcn_mfma_f32_16x16x32_bf16(af[i][1], bfr[j][1], acc[i][j], 0, 0, 0);
      }
    __builtin_amdgcn_s_setprio(0);
    VMC0(); BAR();
  }

  const int rbase = bm * 128 + wm * 64 + lg * 4;
  const int cbase = bn * 128 + wn * 64 + lr;
#pragma unroll
  for (int f = 0; f < 4; f++)
#pragma unroll
    for (int rr = 0; rr < 4; rr++) {
      size_t rowoff = (size_t)(rbase + f * 16 + rr) * N + cbase;
#pragma unroll
      for (int nf = 0; nf < 4; nf++) C[rowoff + nf * 16] = (CT)acc[f][nf][rr];
    }
#undef VMC0
#undef BAR
}

// ---------------- merged postprocess: gates + q/k RMS/RoPE/shift + v-gate/vT ----------------
__global__ __launch_bounds__(512) void k_post(
    const __bf16* __restrict__ qkv, const float* __restrict__ x,
    const float* __restrict__ ve, const float* __restrict__ f1,
    const float* __restrict__ f2, const float* __restrict__ agw,
    const float* __restrict__ vgw, const int* __restrict__ koff_p,
    __bf16* __restrict__ qb, __bf16* __restrict__ kb,
    __bf16* __restrict__ vT, float* __restrict__ ag) {
  __shared__ float vg_lds[32][8];
  __shared__ __bf16 vtile[HD][36];
  const int t0 = blockIdx.x * 32;
  const int tid = threadIdx.x;
  const int h = tid >> 6, l = tid & 63;
  const int d0 = 2 * l;
  const int koff = *koff_p;

  if (tid < 256) {
    const int tl = tid >> 3, hh = tid & 7;
    const int t = t0 + tl;
    float za = 0.0f, zg = 0.0f;
#pragma unroll
    for (int j = 0; j < 12; j++) {
      float xv = x[(size_t)t * DIMM + j];
      za += xv * agw[hh * 12 + j];
      zg += xv * vgw[hh * 12 + j];
    }
    ag[(size_t)t * NHEAD + hh] = sig_(za);
    vg_lds[tl][hh] = 2.0f * sig_(zg);
  }

#pragma unroll 2
  for (int tl = 0; tl < 32; tl++) {
    const int t = t0 + tl;
    const size_t qoff = (size_t)t * (3 * DIMM) + h * HD;

    bfx2 qv = *(const bfx2*)&qkv[qoff + d0];
    bfx2 kv = *(const bfx2*)&qkv[qoff + DIMM + d0];
    float q0 = (float)qv[0], q1 = (float)qv[1];
    float k0 = (float)kv[0], k1 = (float)kv[1];

    float sq = q0 * q0 + q1 * q1;
    float sk = k0 * k0 + k1 * k1;
#pragma unroll
    for (int off = 32; off; off >>= 1) {
      sq += __shfl_xor(sq, off);
      sk += __shfl_xor(sk, off);
    }
    float rq = rsqrtf(sq * (1.0f / 128.0f) + RMS_EPS);
    float rk = rsqrtf(sk * (1.0f / 128.0f) + RMS_EPS);
    q0 *= rq; q1 *= rq; k0 *= rk; k1 *= rk;

    float2 cc = *(const float2*)&f1[(size_t)t * HD + d0];
    float2 ss = *(const float2*)&f2[(size_t)t * HD + d0];
    float rq0 = cc.x * q0 + ss.x * q1, rq1 = cc.y * q1 + ss.y * q0;
    float rk0 = cc.x * k0 + ss.x * k1, rk1 = cc.y * k1 + ss.y * k0;

    bfx2 qo; qo[0] = (__bf16)rq0; qo[1] = (__bf16)rq1;
    *(bfx2*)&qb[(size_t)t * DIMM + h * HD + d0] = qo;

    bfx2 ko2; ko2[0] = (__bf16)rk0; ko2[1] = (__bf16)rk1;
    const size_t kcol = (size_t)h * HD + d0;
    if (!koff || l < 32) {
      *(bfx2*)&kb[(size_t)t * DIMM + kcol] = ko2;
    } else {
      if (t + 1 < TSEQ) *(bfx2*)&kb[(size_t)(t + 1) * DIMM + kcol] = ko2;
      if (t == 0)       *(bfx2*)&kb[kcol] = ko2;
    }
  }
  __syncthreads();

  const int w = tid >> 6;
  const int dout = tid >> 2, tof = (tid & 3) * 8;
  for (int hh = 0; hh < 8; hh++) {
#pragma unroll
    for (int it = 0; it < 4; it++) {
      const int tl = w * 4 + it;
      const int t = t0 + tl;
      const size_t voff = (size_t)t * (3 * DIMM) + 2 * DIMM + hh * HD;
      float va = (float)qkv[voff + l];
      float vb = (float)qkv[voff + l + 64];
      float vea = ve[(size_t)t * DIMM + hh * HD + l];
      float veb = ve[(size_t)t * DIMM + hh * HD + l + 64];
      float gv = vg_lds[tl][hh];
      vtile[l][tl]      = (__bf16)(va + gv * vea);
      vtile[l + 64][tl] = (__bf16)(vb + gv * veb);
    }
    __syncthreads();
    {
      bfx4 a0 = *(const bfx4*)&vtile[dout][tof];
      bfx4 a1 = *(const bfx4*)&vtile[dout][tof + 4];
      bfx8 p0;
      p0[0] = a0[0]; p0[1] = a0[1]; p0[2] = a0[2]; p0[3] = a0[3];
      p0[4] = a1[0]; p0[5] = a1[1]; p0[6] = a1[2]; p0[7] = a1[3];
      *(bfx8*)&vT[(size_t)(hh * HD + dout) * TSEQ + t0 + tof] = p0;
    }
    __syncthreads();
  }
}

// ---------------- LDS-staged windowed varlen flash attention (K/V time-shared) ----------------
// grid (TSEQ/128, NHEAD), 512 threads; 64KB LDS -> 2 blocks/CU (inter-block overlap).
// Sequence: stage K -> vmcnt(0)+bar -> QK^T+softmax (from LDS) -> bar ->
//           stage V into SAME buffer -> vmcnt(0)+bar -> PV (from LDS).
__global__ __launch_bounds__(512, 4) void k_attn3(
    const __bf16* __restrict__ qb, const __bf16* __restrict__ kb,
    const __bf16* __restrict__ vT, const float* __restrict__ ag,
    const int* __restrict__ sl, int ns, __bf16* __restrict__ yb) {
  __shared__ __align__(16) char kls[65536];  // K: 256 rows x 256B; then V: 128 x 512B
  const int n = blockIdx.x, h = blockIdx.y;
  const int tid = threadIdx.x;
  const int w = tid >> 6, l = tid & 63;
  const int lr = l & 15, lg = l >> 4;
  const int q0r = n * 128 + w * 16;
  const int kbase = q0r - 128;
  const int kbb = n * 128 - 128;
  const int q = q0r + lr;
  const int kfs = (q0r < 128) ? ((128 - q0r) >> 4) : 0;

  // Q fragments from global (drained by the K-staging vmcnt)
  bfx8 qf[4];
#pragma unroll
  for (int ds = 0; ds < 4; ds++)
    qf[ds] = *(const bfx8*)&qb[(size_t)q * DIMM + h * HD + ds * 32 + lg * 8];

  // segment lower bound per q-row
  int segs = 0;
  for (int i = 0; i < ns; i++) {
    int v = sl[i];
    segs = (v <= q) ? ((v > segs) ? v : segs) : segs;
  }
  int klo = q - 128;
  if (segs > klo) klo = segs;
  if (klo < 0) klo = 0;
  __builtin_amdgcn_sched_barrier(0);

  // ---- stage K: 8 rounds x 8KB; lane covers (rel row, 16B slot) ----
  {
    const int rr_ = tid >> 4;
    const int slot = tid & 15;
#pragma unroll
    for (int r = 0; r < 8; r++) {
      const int rel = r * 32 + rr_;
      int grow = kbb + rel;
      grow = grow < 0 ? 0 : grow;
      const int slotp = slot ^ (rel & 15);
      GLDS16(kb + (size_t)grow * DIMM + h * HD + slotp * 8,
             kls + r * 8192 + w * 1024);
    }
  }

  __builtin_amdgcn_sched_barrier(0);
  asm volatile("s_waitcnt vmcnt(0)" ::: "memory");  // K (and Q) landed
  __builtin_amdgcn_sched_barrier(0);
  __builtin_amdgcn_s_barrier();

  // ---- S^T = K Q^T over the 144-key window (K frags from LDS) ----
  const int kswz = lr << 4;
  f32x4 sf[9] = {};
#pragma unroll
  for (int kf = 0; kf < 9; kf++) {
    if (kf >= kfs) {
      const int relrow = w * 16 + kf * 16 + lr;
      const char* kp = kls + relrow * 256;
      bfx8 k0 = *(const bfx8*)(kp + ((lg * 16) ^ kswz));
      bfx8 k1 = *(const bfx8*)(kp + ((64 + lg * 16) ^ kswz));
      bfx8 k2 = *(const bfx8*)(kp + ((128 + lg * 16) ^ kswz));
      bfx8 k3 = *(const bfx8*)(kp + ((192 + lg * 16) ^ kswz));
      sf[kf] = __builtin_amdgcn_mfma_f32_16x16x32_bf16(k0, qf[0], sf[kf], 0, 0, 0);
      sf[kf] = __builtin_amdgcn_mfma_f32_16x16x32_bf16(k1, qf[1], sf[kf], 0, 0, 0);
      sf[kf] = __builtin_amdgcn_mfma_f32_16x16x32_bf16(k2, qf[2], sf[kf], 0, 0, 0);
      sf[kf] = __builtin_amdgcn_mfma_f32_16x16x32_bf16(k3, qf[3], sf[kf], 0, 0, 0);
    }
  }

  // mask + scale
#pragma unroll
  for (int kf = 0; kf < 9; kf++)
#pragma unroll
    for (int rr = 0; rr < 4; rr++) {
      int k = kbase + kf * 16 + lg * 4 + rr;
      bool valid = (k >= klo) && (k <= q);
      sf[kf][rr] = valid ? sf[kf][rr] * ATTN_SCALE : -1e30f;
    }

  float mx = -1e30f;
#pragma unroll
  for (int kf = 0; kf < 9; kf++)
#pragma unroll
    for (int rr = 0; rr < 4; rr++) mx = fmaxf(mx, sf[kf][rr]);
  mx = fmaxf(mx, __shfl_xor(mx, 16));
  mx = fmaxf(mx, __shfl_xor(mx, 32));

  float lsum = 0.0f;
#pragma unroll
  for (int kf = 0; kf < 9; kf++)
#pragma unroll
    for (int rr = 0; rr < 4; rr++) {
      float p = __expf(sf[kf][rr] - mx);
      sf[kf][rr] = p;
      lsum += p;
    }
  lsum += __shfl_xor(lsum, 16);
  lsum += __shfl_xor(lsum, 32);

  // all waves finished reading K (ds_reads consumed by MFMA above)
  __builtin_amdgcn_s_barrier();

  // ---- stage V into the SAME buffer: 8 rounds x 8KB ----
  {
    const int slot = l & 31;
#pragma unroll
    for (int r = 0; r < 8; r++) {
      const int d = r * 16 + w * 2 + (l >> 5);
      const int slotp = slot ^ (d & 15);
      int tsrc = kbb + slotp * 8;
      tsrc = tsrc < 0 ? 0 : tsrc;
      GLDS16(vT + (size_t)(h * HD + d) * TSEQ + tsrc,
             kls + r * 8192 + w * 1024);
    }
  }

  __builtin_amdgcn_sched_barrier(0);
  asm volatile("s_waitcnt vmcnt(0)" ::: "memory");  // V landed
  __builtin_amdgcn_sched_barrier(0);
  __builtin_amdgcn_s_barrier();

  // ---- O^T = V^T P^T via 16x16x16 MFMAs (V frags from LDS) ----
  f32x4 o[8] = {};
#pragma unroll
  for (int kf = 0; kf < 9; kf++) {
    if (kf >= kfs) {
      bfx4 pc;
      pc[0] = (__bf16)sf[kf][0]; pc[1] = (__bf16)sf[kf][1];
      pc[2] = (__bf16)sf[kf][2]; pc[3] = (__bf16)sf[kf][3];
      s16x4 pb = *(s16x4*)&pc;
      const int tof = (w * 32 + kf * 32 + lg * 8) ^ kswz;
#pragma unroll
      for (int nf = 0; nf < 8; nf++) {
        s16x4 vf = *(const s16x4*)(kls + (nf * 16 + lr) * 512 + tof);
        o[nf] = __builtin_amdgcn_mfma_f32_16x16x16bf16_1k(vf, pb, o[nf], 0, 0, 0);
      }
    }
  }

  const float sc = ag[(size_t)q * NHEAD + h] / lsum;
#pragma unroll
  for (int nf = 0; nf < 8; nf++) {
    bfx4 st;
#pragma unroll
    for (int rr = 0; rr < 4; rr++) st[rr] = (__bf16)(o[nf][rr] * sc);
    *(bfx4*)&yb[(size_t)q * DIMM + h * HD + nf * 16 + lg * 4] = st;
  }
}

// ---------------- launch ----------------
extern "C" void kernel_launch(void* const* d_in, const int* in_sizes, int n_in,
                              void* d_out, int out_size, void* d_ws, size_t ws_size,
                              hipStream_t stream) {
  const float* x   = (const float*)d_in[0];
  const float* qw  = (const float*)d_in[1];
  const float* ve  = (const float*)d_in[2];
  const float* lam = (const float*)d_in[3];
  const float* f1  = (const float*)d_in[4];
  const float* f2  = (const float*)d_in[5];
  const float* agw = (const float*)d_in[6];
  const float* vgw = (const float*)d_in[7];
  const int*   sl  = (const int*)d_in[8];
  const int    ns  = in_sizes[8];
  const int*   koff = (const int*)d_in[10];
  float* out = (float*)d_out;
  char* ws = (char*)d_ws;

  const size_t MB = 1024 * 1024;
  if (ws_size < 105 * MB) return;
  __bf16* xb   = (__bf16*)(ws);
  __bf16* w1b  = (__bf16*)(ws + 16 * MB);
  __bf16* w2b  = (__bf16*)(ws + 22 * MB);
  __bf16* qkvb = (__bf16*)(ws + 24 * MB);
  __bf16* qbuf = (__bf16*)(ws + 72 * MB);
  __bf16* kbuf = (__bf16*)(ws + 88 * MB);
  float*  ag   = (float*)(ws + 104 * MB);
  __bf16* vT   = xb;    // xb dead after GEMM1
  __bf16* ybuf = qkvb;  // qkvb dead after k_post

  k_prep<<<3072, 256, 0, stream>>>((const float4*)x, (const float4*)qw, lam,
                                   (bfx4*)xb, (bfx4*)w1b, (bfx4*)w2b);
  k_gemm2b<__bf16><<<dim3(TSEQ / 128, 3 * DIMM / 128), 256, 0, stream>>>(
      xb, w1b, qkvb, TSEQ, 3 * DIMM, DIMM);
  k_post<<<TSEQ / 32, 512, 0, stream>>>(qkvb, x, ve, f1, f2, agw, vgw, koff,
                                        qbuf, kbuf, vT, ag);
  k_attn3<<<dim3(TSEQ / 128, NHEAD), 512, 0, stream>>>(qbuf, kbuf, vT, ag, sl, ns, ybuf);
  k_gemm2b<float><<<dim3(TSEQ / 128, DIMM / 128), 256, 0, stream>>>(
      ybuf, w2b, out, TSEQ, DIMM, DIMM);
}